// Round 8
// baseline (324.964 us; speedup 1.0000x reference)
//
#include <hip/hip_runtime.h>

#define SEQ  2048
#define DIM  1024
#define NTOK 8192   // 4*SEQ
#define NQKV 3072
#define BK   64

typedef __attribute__((ext_vector_type(8)))  __bf16 bf16x8;
typedef __attribute__((ext_vector_type(16))) float  f32x16;

__device__ __forceinline__ unsigned short f2bf(float f) {
    unsigned int u = __float_as_uint(f);
    u += 0x7fffu + ((u >> 16) & 1u);          // round-to-nearest-even
    return (unsigned short)(u >> 16);
}

__device__ __forceinline__ void load_lds_128(const unsigned short* g, unsigned short* l) {
    __builtin_amdgcn_global_load_lds(
        (const __attribute__((address_space(1))) void*)g,
        (__attribute__((address_space(3))) void*)l, 16, 0, 0);
}

// ---------------------------------------------------------------------------
// NT GEMM, bf16 MFMA 32x32x16, 128x128 block, BK=64, 4 waves (2x2 of 64x64).
// R4-proven core: rotate-by-row 16B-chunk swizzle (conflicts at structural
// 8-wrap minimum), 2-barrier K-loop, plain 3D grid (m-tile fastest).
// MODE 0: fused QKV epilogue (q,k bf16 + bias; v transposed into vt + bias)
// MODE 2: bf16 P = exp(acc*alpha) + fused rowsum atomicAdd into rs
// MODE 1: SPLIT-K=2 (blockIdx.z = z*2+kp, each block does K/2):
//         atomicAdd fp32 C += acc / rs[row]  (out pre-zeroed by memset).
//         Rationale (R7): GEMM3 was grid-capped at 2 blocks/CU (512 blocks);
//         wall tracked block-iters/residency -> split-K doubles residency
//         at constant total block-iters.
// ---------------------------------------------------------------------------
template <int MODE>
__global__ __launch_bounds__(256)
void gemm_bt(const unsigned short* __restrict__ A, const unsigned short* __restrict__ B,
             void* __restrict__ Cv,
             const float* __restrict__ b0, const float* __restrict__ b1,
             const float* __restrict__ b2, unsigned short* __restrict__ vt,
             float* __restrict__ rs,
             int K, int lda, int ldb, int ldc,
             long sA, long sB, long sC, float alpha)
{
    __shared__ unsigned short As[128 * BK];   // 16 KB
    __shared__ unsigned short Bs[128 * BK];   // 16 KB

    const int tid  = threadIdx.x;
    const int wave = tid >> 6;
    const int lane = tid & 63;
    const int l31  = lane & 31;
    const int half = lane >> 5;

    const int m0 = blockIdx.x * 128;
    const int n0 = blockIdx.y * 128;
    int z = blockIdx.z;
    int kp = 0;
    if (MODE == 1) { kp = z & 1; z >>= 1; }   // split-K decode
    A += (long)z * sA + (long)kp * 1024;      // K-half offset (lda-contig dim)
    B += (long)z * sB + (long)kp * 1024;

    const int wm = (wave >> 1) * 64;
    const int wn = (wave & 1) * 64;

    f32x16 acc[2][2] = {};

    // ---- staging map: chunk ch = tid + 256p -> row ch>>3, slot ch&7 ----
    // row r_p = (tid>>3) + 32p; slot c = tid&7; global chunk g = (c - r) & 7
    const int r0 = tid >> 3;
    const int g  = ((tid & 7) - r0) & 7;
    const unsigned short* Ag = A + (long)(m0 + r0) * lda + g * 8;
    const unsigned short* Bg = B + (long)(n0 + r0) * ldb + g * 8;
    unsigned short* Al = As + tid * 8;
    unsigned short* Bl = Bs + tid * 8;

    // ---- fragment LDS offsets (lane-constant), un-rotated ----
    const unsigned short* Af[2][4];
    const unsigned short* Bf[2][4];
#pragma unroll
    for (int i = 0; i < 2; ++i) {
        const int rrA = wm + i * 32 + l31;
        const int rrB = wn + i * 32 + l31;
#pragma unroll
        for (int h = 0; h < 4; ++h) {
            const int gw = h * 2 + half;
            Af[i][h] = As + rrA * BK + (((gw + rrA) & 7) << 3);
            Bf[i][h] = Bs + rrB * BK + (((gw + rrB) & 7) << 3);
        }
    }

    for (int k0 = 0; k0 < K; k0 += BK) {
#pragma unroll
        for (int p = 0; p < 4; ++p) {
            load_lds_128(Ag + k0 + (long)(32 * p) * lda, Al + 2048 * p);
            load_lds_128(Bg + k0 + (long)(32 * p) * ldb, Bl + 2048 * p);
        }
        __syncthreads();                       // vmcnt(0) drain + barrier
        bf16x8 a[2][4], b[2][4];
#pragma unroll
        for (int i = 0; i < 2; ++i)
#pragma unroll
            for (int h = 0; h < 4; ++h) {
                a[i][h] = *(const bf16x8*)Af[i][h];
                b[i][h] = *(const bf16x8*)Bf[i][h];
            }
#pragma unroll
        for (int h = 0; h < 4; ++h)
#pragma unroll
            for (int i = 0; i < 2; ++i)
#pragma unroll
                for (int j = 0; j < 2; ++j)
                    acc[i][j] = __builtin_amdgcn_mfma_f32_32x32x16_bf16(
                        a[i][h], b[j][h], acc[i][j], 0, 0, 0);
        __syncthreads();
    }

    // C/D: col = lane&31, row = (reg&3) + 8*(reg>>2) + 4*(lane>>5)  [m74/m101]
    if (MODE == 0) {
        if (n0 >= 2048) {
            // V columns -> vt[b][d][m] (+bias), packed 4-m ushort4 stores
#pragma unroll
            for (int j = 0; j < 2; ++j) {
                const int d = n0 - 2048 + wn + j * 32 + l31;
                const float bias = b2[d];
#pragma unroll
                for (int i = 0; i < 2; ++i) {
                    const int mbase = m0 + wm + i * 32 + 4 * half;
#pragma unroll
                    for (int rq = 0; rq < 4; ++rq) {
                        const int rowi = mbase + 8 * rq;
                        const int bb = rowi >> 11;
                        const int mm = rowi & 2047;
                        ushort4 u;
                        u.x = f2bf(acc[i][j][rq * 4 + 0] + bias);
                        u.y = f2bf(acc[i][j][rq * 4 + 1] + bias);
                        u.z = f2bf(acc[i][j][rq * 4 + 2] + bias);
                        u.w = f2bf(acc[i][j][rq * 4 + 3] + bias);
                        *(ushort4*)(vt + ((long)bb * DIM + d) * SEQ + mm) = u;
                    }
                }
            }
        } else {
            unsigned short* C16 = (unsigned short*)Cv;
#pragma unroll
            for (int j = 0; j < 2; ++j) {
                const int col = n0 + wn + j * 32 + l31;
                const float* bp = (col >> 10) ? b1 : b0;
                const float bias = bp[col & 1023];
#pragma unroll
                for (int i = 0; i < 2; ++i)
#pragma unroll
                    for (int r = 0; r < 16; ++r) {
                        const int rowi = m0 + wm + i * 32 + (r & 3) + 8 * (r >> 2) + 4 * half;
                        C16[(long)rowi * ldc + col] = f2bf(acc[i][j][r] + bias);
                    }
            }
        }
    } else if (MODE == 2) {
        // P = exp(acc*alpha) bf16 + fused rowsum (shfl over 32 col-lanes)
        unsigned short* C16 = (unsigned short*)Cv + (long)z * sC;
        float* rsz = rs + (long)z * SEQ;
#pragma unroll
        for (int i = 0; i < 2; ++i)
#pragma unroll
            for (int r = 0; r < 16; ++r) {
                const int rowi = m0 + wm + i * 32 + (r & 3) + 8 * (r >> 2) + 4 * half;
                const float p0 = __expf(acc[i][0][r] * alpha);
                const float p1 = __expf(acc[i][1][r] * alpha);
                C16[(long)rowi * ldc + n0 + wn + l31]      = f2bf(p0);
                C16[(long)rowi * ldc + n0 + wn + 32 + l31] = f2bf(p1);
                float v = p0 + p1;
                v += __shfl_xor(v, 1);  v += __shfl_xor(v, 2);
                v += __shfl_xor(v, 4);  v += __shfl_xor(v, 8);
                v += __shfl_xor(v, 16);
                if (l31 == 0) atomicAdd(rsz + rowi, v);
            }
    } else {  // MODE 1: split-K partial, C += acc / rs[row] via atomics
        float* C = (float*)Cv + (long)z * sC;
        const float* rsz = rs + (long)z * SEQ;
#pragma unroll
        for (int i = 0; i < 2; ++i) {
            const int rbase = m0 + wm + i * 32 + 4 * half;
#pragma unroll
            for (int rq = 0; rq < 4; ++rq) {
                const float4 s4 = *(const float4*)(rsz + rbase + 8 * rq);
                float4 inv4;
                inv4.x = 1.0f / s4.x; inv4.y = 1.0f / s4.y;
                inv4.z = 1.0f / s4.z; inv4.w = 1.0f / s4.w;
#pragma unroll
                for (int j = 0; j < 2; ++j) {
                    const int col = n0 + wn + j * 32 + l31;
                    atomicAdd(&C[(long)(rbase + 8 * rq + 0) * ldc + col], acc[i][j][rq * 4 + 0] * inv4.x);
                    atomicAdd(&C[(long)(rbase + 8 * rq + 1) * ldc + col], acc[i][j][rq * 4 + 1] * inv4.y);
                    atomicAdd(&C[(long)(rbase + 8 * rq + 2) * ldc + col], acc[i][j][rq * 4 + 2] * inv4.z);
                    atomicAdd(&C[(long)(rbase + 8 * rq + 3) * ldc + col], acc[i][j][rq * 4 + 3] * inv4.w);
                }
            }
        }
    }
}

// ---------------------------------------------------------------------------
// Single launch: convert x (8192x1024) and Wq|Wk|Wv (each 1024x1024) to bf16.
// ---------------------------------------------------------------------------
__global__ __launch_bounds__(256)
void cvt_all(const float* __restrict__ x, const float* __restrict__ Wq,
             const float* __restrict__ Wk, const float* __restrict__ Wv,
             unsigned short* __restrict__ xb, unsigned short* __restrict__ Wb)
{
    const long NX = (long)NTOK * DIM / 4;     // 2M float4 groups
    const long NW = (long)DIM * DIM / 4;      // 256K
    long i = (long)blockIdx.x * 256 + threadIdx.x;
    const float* src;
    unsigned short* dst;
    long j;
    if (i < NX)               { src = x;  dst = xb;                 j = i; }
    else if (i < NX + NW)     { src = Wq; dst = Wb;                 j = i - NX; }
    else if (i < NX + 2 * NW) { src = Wk; dst = Wb + DIM * DIM;     j = i - NX - NW; }
    else                      { src = Wv; dst = Wb + 2 * DIM * DIM; j = i - NX - 2 * NW; }
    float4 f = ((const float4*)src)[j];
    ushort4 u;
    u.x = f2bf(f.x); u.y = f2bf(f.y); u.z = f2bf(f.z); u.w = f2bf(f.w);
    ((ushort4*)dst)[j] = u;
}

// ---------------------------------------------------------------------------
extern "C" void kernel_launch(void* const* d_in, const int* in_sizes, int n_in,
                              void* d_out, int out_size, void* d_ws, size_t ws_size,
                              hipStream_t stream)
{
    const float* x  = (const float*)d_in[0];
    const float* Wq = (const float*)d_in[1];
    const float* bq = (const float*)d_in[2];
    const float* Wk = (const float*)d_in[3];
    const float* bk = (const float*)d_in[4];
    const float* Wv = (const float*)d_in[5];
    const float* bv = (const float*)d_in[6];
    float* out = (float*)d_out;

    // Workspace (>=167.8MB proven R1):
    //  [0,16MB):    xb bf16 [8192][1024]
    //  [16,22MB):   Wb bf16 [3][1024][1024]
    //  [64,112MB):  qkv bf16 [8192][3072]  (V cols never written; vt instead)
    //  [112,128MB): vt  bf16 [4][1024][2048]
    //  [128,160MB): P   bf16 [4][2048][2048]  (unnormalized exp)
    //  [160MB,+32KB): rs fp32 [4][2048] (atomic rowsums)
    char* ws = (char*)d_ws;
    unsigned short* xb   = (unsigned short*)ws;
    unsigned short* Wb   = (unsigned short*)(ws + 16u * 1024 * 1024);
    unsigned short* qkv  = (unsigned short*)(ws + 64u * 1024 * 1024);
    unsigned short* vt   = (unsigned short*)(ws + 112u * 1024 * 1024);
    unsigned short* P    = (unsigned short*)(ws + 128u * 1024 * 1024);
    float*          rs   = (float*)(ws + 160u * 1024 * 1024);

    const float scale = 0.03125f;   // 1/sqrt(1024)
    dim3 blk(256);

    // 0) zero the atomic targets up front (off the critical path)
    hipMemsetAsync(rs, 0, 4 * SEQ * sizeof(float), stream);
    hipMemsetAsync(out, 0, (size_t)out_size * sizeof(float), stream);

    // 1) converts (single launch)
    cvt_all<<<(NTOK * DIM / 4 + 3 * DIM * DIM / 4) / 256, blk, 0, stream>>>(
        x, Wq, Wk, Wv, xb, Wb);

    // 2) fused QKV projection (V transposed into vt in-epilogue)
    gemm_bt<0><<<dim3(NTOK / 128, NQKV / 128), blk, 0, stream>>>(
        xb, Wb, qkv, bq, bk, bv, vt, nullptr,
        DIM, DIM, DIM, NQKV, 0, 0, 0, 1.0f);

    // 3) P[b] = exp(q[b] . k[b]^T * scale)  bf16, + fused rowsum atomics
    gemm_bt<2><<<dim3(SEQ / 128, SEQ / 128, 4), blk, 0, stream>>>(
        qkv, qkv + 1024, P, nullptr, nullptr, nullptr, nullptr, rs,
        DIM, NQKV, NQKV, SEQ,
        (long)SEQ * NQKV, (long)SEQ * NQKV, (long)SEQ * SEQ, scale);

    // 4) out[b] += (P[b][,kp-half] . vt[b][,kp-half]^T) / rs  (split-K=2)
    gemm_bt<1><<<dim3(SEQ / 128, DIM / 128, 8), blk, 0, stream>>>(
        P, vt, out, nullptr, nullptr, nullptr, nullptr, rs,
        1024, SEQ, SEQ, DIM,
        (long)SEQ * SEQ, (long)DIM * SEQ, (long)SEQ * DIM, 1.0f);
}